// Round 3
// baseline (366.184 us; speedup 1.0000x reference)
//
#include <hip/hip_runtime.h>
#include <hip/hip_bf16.h>

// GRNN fused implementation. VOCAB=100000, D=300, H=50, S=64, W=32, OUT=5.
// All inputs fp32 (proven: round-1 bf16 reads -> NaN), output fp32 (proven:
// round-2 bf16 writes decoded as fp32 matched words 0-1, zeroed words 2-4).
//
// Algebra: conv branches only need window-means over w of p = x@wl^T + b;
// all 6 windows derive from colsum(x) minus edge rows x0,x1,x30,x31 -> 5
// matvecs (50x300) per sentence instead of a 32x50x300 matmul (6.4x FLOP cut).
// Scan: input projections precomputed in parallel; recurrent part runs one
// wave per direction with weights in VGPRs and h broadcast via readlane.

// ---------------- Kernel 1: rep[64,50] -------------------------------------
// One block per sentence s, 320 threads (5 waves).
__global__ __launch_bounds__(320) void rep_kernel(
    const int* __restrict__ doc, const float* __restrict__ emb,
    const float* __restrict__ wl_w, const float* __restrict__ wl_b,
    const float* __restrict__ c1w, const float* __restrict__ c1b,
    const float* __restrict__ c2w, const float* __restrict__ c2b,
    const float* __restrict__ c3w, const float* __restrict__ c3b,
    float* __restrict__ rep_out)
{
    __shared__ int docs[32];
    __shared__ float xL[32][300];   // gathered embedding rows
    __shared__ float sv[5][300];    // [colsum, x0, x1, x30, x31]
    __shared__ float P[5][50];      // wl_w @ sv_v
    __shared__ float m[6][50];      // the 6 window means (p-space)

    const int s = blockIdx.x, tid = threadIdx.x;
    if (tid < 32) docs[tid] = doc[s * 32 + tid];
    __syncthreads();

    // Stage 1: gather 32 rows x 300 fp32. 10 threads/row, 15 float2 each.
    {
        const int w = tid / 10, part = tid - w * 10;
        const float2* row = (const float2*)(emb + docs[w] * 300);
#pragma unroll
        for (int t = 0; t < 15; ++t) {
            float2 v = row[part * 15 + t];
            const int d = (part * 15 + t) * 2;
            xL[w][d]     = v.x;
            xL[w][d + 1] = v.y;
        }
    }
    __syncthreads();

    // Stage 1b: column sums + edge rows.
    if (tid < 300) {
        float a = 0.f;
#pragma unroll
        for (int w = 0; w < 32; ++w) a += xL[w][tid];
        sv[0][tid] = a;
        sv[1][tid] = xL[0][tid];
        sv[2][tid] = xL[1][tid];
        sv[3][tid] = xL[30][tid];
        sv[4][tid] = xL[31][tid];
    }
    __syncthreads();

    // Stage 2: P[v][i] = wl_w[i,:] . sv[v,:]  (250 dots of length 300)
    if (tid < 250) {
        const int i = tid / 5, v = tid - (tid / 5) * 5;
        const float2* wrow = (const float2*)(wl_w + i * 300);
        float acc = 0.f;
        for (int d2 = 0; d2 < 150; ++d2) {
            float2 wv = wrow[d2];
            acc = fmaf(wv.x, sv[v][2 * d2], fmaf(wv.y, sv[v][2 * d2 + 1], acc));
        }
        P[v][i] = acc;
    }
    __syncthreads();

    // Stage 3: the 6 window means. mean = Qwin/len + wl_b.
    if (tid < 50) {
        const int i = tid;
        const float b  = wl_b[i];
        const float QA = P[0][i], Q0 = P[1][i], Q1 = P[2][i],
                    Q30 = P[3][i], Q31 = P[4][i];
        m[0][i] = QA * (1.f / 32.f) + b;                 // k=1 rows 0..31
        m[1][i] = (QA - Q31) * (1.f / 31.f) + b;         // k=2 rows 0..30
        m[2][i] = (QA - Q0)  * (1.f / 31.f) + b;         // k=2 rows 1..31
        m[3][i] = (QA - Q30 - Q31) * (1.f / 30.f) + b;   // k=3 rows 0..29
        m[4][i] = (QA - Q0  - Q31) * (1.f / 30.f) + b;   // k=3 rows 1..30
        m[5][i] = (QA - Q0  - Q1 ) * (1.f / 30.f) + b;   // k=3 rows 2..31
    }
    __syncthreads();

    // Stage 4: conv branches + tanh + average.
    if (tid < 50) {
        const int o = tid;
        float y1 = c1b[o], y2 = c2b[o], y3 = c3b[o];
        for (int i = 0; i < 50; ++i) {
            y1 = fmaf(c1w[o * 50 + i], m[0][i], y1);
            const float2 w2 = ((const float2*)c2w)[o * 50 + i];   // [50,50,2]
            y2 = fmaf(w2.x, m[1][i], fmaf(w2.y, m[2][i], y2));
            y3 = fmaf(c3w[(o * 50 + i) * 3 + 0], m[3][i], y3);
            y3 = fmaf(c3w[(o * 50 + i) * 3 + 1], m[4][i], y3);
            y3 = fmaf(c3w[(o * 50 + i) * 3 + 2], m[5][i], y3);
        }
        rep_out[s * 50 + o] = (tanhf(y1) + tanhf(y2) + tanhf(y3)) * (1.f / 3.f);
    }
}

// ---------------- Kernel 2: bidirectional scan + output --------------------
// 1 block, 512 threads. Phase 1 (parallel): input projections for all steps.
// Phase 2 (serial): wave 0 = forward, wave 1 = backward; recurrent weights in
// VGPRs, h broadcast via readlane -> no LDS/barrier in the 64-step loop.
__global__ __launch_bounds__(512) void scan_kernel(
    const float* __restrict__ rep, float* __restrict__ preW,
    const float* __restrict__ fi_w, const float* __restrict__ fi_b,
    const float* __restrict__ ff_w, const float* __restrict__ ff_b,
    const float* __restrict__ fg_w, const float* __restrict__ fg_b,
    const float* __restrict__ bi_w, const float* __restrict__ bi_b,
    const float* __restrict__ bf_w, const float* __restrict__ bf_b,
    const float* __restrict__ bg_w, const float* __restrict__ bg_b,
    const float* __restrict__ out_w, const float* __restrict__ out_b,
    float* __restrict__ outp)
{
    __shared__ float mh[2][50];
    const int tid = threadIdx.x;

    // Phase 1: preW[g][s][o] = B_g[o] + W_g[o,0:50] . rep[srow]
    {
        const float* Ws[6] = { fi_w, ff_w, fg_w, bi_w, bf_w, bg_w };
        const float* Bs[6] = { fi_b, ff_b, fg_b, bi_b, bf_b, bg_b };
        for (int idx = tid; idx < 6 * 64 * 50; idx += 512) {
            const int g  = idx / 3200;
            const int r  = idx - g * 3200;
            const int s2 = r / 50;
            const int o  = r - s2 * 50;
            const int srow = (g < 3) ? s2 : (63 - s2);
            const float2* wrow = (const float2*)(Ws[g] + o * 100);  // W[o, 0:50]
            const float* rr = rep + srow * 50;
            float acc = Bs[g][o];
#pragma unroll
            for (int j2 = 0; j2 < 25; ++j2) {
                float2 wv = wrow[j2];
                acc = fmaf(wv.x, rr[2 * j2], fmaf(wv.y, rr[2 * j2 + 1], acc));
            }
            preW[g * 3200 + s2 * 50 + o] = acc;
        }
    }
    __syncthreads();

    // Phase 2: sequential scans.
    const int wv = tid >> 6, lane = tid & 63;
    if (wv < 2) {
        const int oc = (lane < 50) ? lane : 0;              // shadow lanes
        const float* WiP = wv ? bi_w : fi_w;
        const float* WfP = wv ? bf_w : ff_w;
        const float* WgP = wv ? bg_w : fg_w;
        float wi[50], wf[50], wg[50];                       // W[o, 50+j]
#pragma unroll
        for (int j2 = 0; j2 < 25; ++j2) {
            float2 a = ((const float2*)(WiP + oc * 100 + 50))[j2];
            float2 b = ((const float2*)(WfP + oc * 100 + 50))[j2];
            float2 c = ((const float2*)(WgP + oc * 100 + 50))[j2];
            wi[2*j2] = a.x; wi[2*j2+1] = a.y;
            wf[2*j2] = b.x; wf[2*j2+1] = b.y;
            wg[2*j2] = c.x; wg[2*j2+1] = c.y;
        }
        const float* pi = preW + (wv * 3 + 0) * 3200;
        const float* pf = preW + (wv * 3 + 1) * 3200;
        const float* pg = preW + (wv * 3 + 2) * 3200;

        float h = 0.f, hsum = 0.f;
        float nai = pi[oc], naf = pf[oc], nag = pg[oc];
#pragma unroll 1
        for (int s2 = 0; s2 < 64; ++s2) {
            float ai = nai, af = naf, ag = nag;
            if (s2 < 63) {                                  // prefetch next step
                nai = pi[(s2 + 1) * 50 + oc];
                naf = pf[(s2 + 1) * 50 + oc];
                nag = pg[(s2 + 1) * 50 + oc];
            }
#pragma unroll
            for (int j = 0; j < 50; ++j) {
                float hj = __uint_as_float(
                    (unsigned)__builtin_amdgcn_readlane(__float_as_uint(h), j));
                ai = fmaf(wi[j], hj, ai);
                af = fmaf(wf[j], hj, af);
                ag = fmaf(wg[j], hj, ag);
            }
            const float iv = 1.f / (1.f + __expf(-ai));
            const float fv = 1.f / (1.f + __expf(-af));
            const float gv = tanhf(ag);
            h = tanhf(fmaf(iv, gv, fv * h));
            hsum += h;
        }
        if (lane < 50) mh[wv][lane] = hsum * (1.f / 64.f);
    }
    __syncthreads();

    // Output layer + softmax. Output written as fp32.
    if (tid == 0) {
        float l[5];
        float mx = -3.4e38f;
#pragma unroll
        for (int k = 0; k < 5; ++k) {
            float acc = out_b[k];
            const float2* wrow = (const float2*)(out_w + k * 100);
            for (int j2 = 0; j2 < 25; ++j2) {
                float2 w = wrow[j2];
                acc = fmaf(w.x, mh[0][2*j2], fmaf(w.y, mh[0][2*j2+1], acc));
            }
            for (int j2 = 0; j2 < 25; ++j2) {
                float2 w = wrow[25 + j2];
                acc = fmaf(w.x, mh[1][2*j2], fmaf(w.y, mh[1][2*j2+1], acc));
            }
            l[k] = acc;
            mx = fmaxf(mx, acc);
        }
        float se = 0.f;
#pragma unroll
        for (int k = 0; k < 5; ++k) { l[k] = __expf(l[k] - mx); se += l[k]; }
        const float inv = 1.f / se;
#pragma unroll
        for (int k = 0; k < 5; ++k) outp[k] = l[k] * inv;
    }
}

extern "C" void kernel_launch(void* const* d_in, const int* in_sizes, int n_in,
                              void* d_out, int out_size, void* d_ws, size_t ws_size,
                              hipStream_t stream)
{
    (void)in_sizes; (void)n_in; (void)out_size; (void)ws_size;
    const int*   doc  = (const int*)  d_in[0];
    const float* emb  = (const float*)d_in[1];
    const float* wl_w = (const float*)d_in[2];
    const float* wl_b = (const float*)d_in[3];
    const float* c1w  = (const float*)d_in[4];
    const float* c1b  = (const float*)d_in[5];
    const float* c2w  = (const float*)d_in[6];
    const float* c2b  = (const float*)d_in[7];
    const float* c3w  = (const float*)d_in[8];
    const float* c3b  = (const float*)d_in[9];
    const float* fiw  = (const float*)d_in[10];
    const float* fib  = (const float*)d_in[11];
    const float* ffw  = (const float*)d_in[12];
    const float* ffb  = (const float*)d_in[13];
    const float* fgw  = (const float*)d_in[14];
    const float* fgb  = (const float*)d_in[15];
    const float* biw  = (const float*)d_in[16];
    const float* bib  = (const float*)d_in[17];
    const float* bfw  = (const float*)d_in[18];
    const float* bfb  = (const float*)d_in[19];
    const float* bgw  = (const float*)d_in[20];
    const float* bgb  = (const float*)d_in[21];
    const float* ow   = (const float*)d_in[22];
    const float* ob   = (const float*)d_in[23];

    float* rep = (float*)d_ws;          // 64*50 floats
    float* pre = rep + 64 * 50;         // 6*64*50 floats

    rep_kernel<<<64, 320, 0, stream>>>(doc, emb, wl_w, wl_b,
                                       c1w, c1b, c2w, c2b, c3w, c3b, rep);
    scan_kernel<<<1, 512, 0, stream>>>(rep, pre,
                                       fiw, fib, ffw, ffb, fgw, fgb,
                                       biw, bib, bfw, bfb, bgw, bgb,
                                       ow, ob, (float*)d_out);
}

// Round 4
// 267.740 us; speedup vs baseline: 1.3677x; 1.3677x over previous
//
#include <hip/hip_runtime.h>

// GRNN fused implementation. VOCAB=100000, D=300, H=50, S=64, W=32, OUT=5.
// All fp32 in/out (established rounds 0-3).
//
// Round-4 change: round-3's scan held 150 weight floats/lane in one wave ->
// spilled to scratch at VGPR_Count=88 -> 64 serial steps x 150 scratch loads
// = 160us. Now 6 waves (direction x gate), 50 weights/lane (no spill
// possible at the granted budget), double-buffered LDS + 1 barrier/step.
// Input projections moved into rep_kernel (parallel across 64 blocks).
//
// Algebra: conv branches only need window-means over w of p = x@wl^T + b;
// all 6 windows derive from colsum(x) minus edge rows x0,x1,x30,x31 -> 5
// matvecs (50x300) per sentence instead of a 32x50x300 matmul. Reversal of
// h_b before the mean is a no-op (mean over steps), so bwd scan just
// consumes rep in reverse order via the projection indexing.

__device__ __forceinline__ float rl(float v, int j) {
    return __uint_as_float((unsigned)__builtin_amdgcn_readlane(__float_as_uint(v), j));
}
__device__ __forceinline__ float sigm(float x) { return 1.f / (1.f + __expf(-x)); }
__device__ __forceinline__ float tanh_fast(float x) {
    return 1.f - 2.f / (__expf(2.f * x) + 1.f);   // exact at +-inf, ~1e-7 abs err
}

// ---------------- Kernel 1: rep + gate input-projections --------------------
// One block per sentence s, 320 threads (5 waves).
__global__ __launch_bounds__(320, 1) void rep_kernel(
    const int* __restrict__ doc, const float* __restrict__ emb,
    const float* __restrict__ wl_w, const float* __restrict__ wl_b,
    const float* __restrict__ c1w, const float* __restrict__ c1b,
    const float* __restrict__ c2w, const float* __restrict__ c2b,
    const float* __restrict__ c3w, const float* __restrict__ c3b,
    const float* __restrict__ fiw, const float* __restrict__ fib,
    const float* __restrict__ ffw, const float* __restrict__ ffb,
    const float* __restrict__ fgw, const float* __restrict__ fgb,
    const float* __restrict__ biw, const float* __restrict__ bib,
    const float* __restrict__ bfw, const float* __restrict__ bfb,
    const float* __restrict__ bgw, const float* __restrict__ bgb,
    float* __restrict__ preW)            // [6][64][50]
{
    __shared__ int docs[32];
    __shared__ float xL[32][300];   // gathered embedding rows
    __shared__ float sv[5][300];    // [colsum, x0, x1, x30, x31]
    __shared__ float P[5][50];      // wl_w @ sv_v
    __shared__ float m[6][50];      // the 6 window means (p-space)
    __shared__ float r[50];         // rep[s]

    const int s = blockIdx.x, tid = threadIdx.x;
    if (tid < 32) docs[tid] = doc[s * 32 + tid];
    __syncthreads();

    // Stage 1: gather 32 rows x 300 fp32. 10 threads/row, 15 float2 each.
    {
        const int w = tid / 10, part = tid - w * 10;
        const float2* row = (const float2*)(emb + docs[w] * 300);
#pragma unroll
        for (int t = 0; t < 15; ++t) {
            float2 v = row[part * 15 + t];
            const int d = (part * 15 + t) * 2;
            xL[w][d]     = v.x;
            xL[w][d + 1] = v.y;
        }
    }
    __syncthreads();

    // Stage 1b: column sums + edge rows.
    if (tid < 300) {
        float a = 0.f;
#pragma unroll
        for (int w = 0; w < 32; ++w) a += xL[w][tid];
        sv[0][tid] = a;
        sv[1][tid] = xL[0][tid];
        sv[2][tid] = xL[1][tid];
        sv[3][tid] = xL[30][tid];
        sv[4][tid] = xL[31][tid];
    }
    __syncthreads();

    // Stage 2: P[v][i] = wl_w[i,:] . sv[v,:]
    if (tid < 250) {
        const int i = tid / 5, v = tid - (tid / 5) * 5;
        const float2* wrow = (const float2*)(wl_w + i * 300);
        float a0 = 0.f, a1 = 0.f;
#pragma unroll 5
        for (int d2 = 0; d2 < 150; ++d2) {
            float2 wv = wrow[d2];
            a0 = fmaf(wv.x, sv[v][2 * d2],     a0);
            a1 = fmaf(wv.y, sv[v][2 * d2 + 1], a1);
        }
        P[v][i] = a0 + a1;
    }
    __syncthreads();

    // Stage 3: the 6 window means. mean = Qwin/len + wl_b.
    if (tid < 50) {
        const int i = tid;
        const float b  = wl_b[i];
        const float QA = P[0][i], Q0 = P[1][i], Q1 = P[2][i],
                    Q30 = P[3][i], Q31 = P[4][i];
        m[0][i] = QA * (1.f / 32.f) + b;
        m[1][i] = (QA - Q31) * (1.f / 31.f) + b;
        m[2][i] = (QA - Q0)  * (1.f / 31.f) + b;
        m[3][i] = (QA - Q30 - Q31) * (1.f / 30.f) + b;
        m[4][i] = (QA - Q0  - Q31) * (1.f / 30.f) + b;
        m[5][i] = (QA - Q0  - Q1 ) * (1.f / 30.f) + b;
    }
    __syncthreads();

    // Stage 4: conv branches + tanh + average -> r[o].
    if (tid < 50) {
        const int o = tid;
        float y1 = c1b[o], y2 = c2b[o], y3 = c3b[o];
        for (int i = 0; i < 50; ++i) {
            y1 = fmaf(c1w[o * 50 + i], m[0][i], y1);
            const float2 w2 = ((const float2*)c2w)[o * 50 + i];
            y2 = fmaf(w2.x, m[1][i], fmaf(w2.y, m[2][i], y2));
            y3 = fmaf(c3w[(o * 50 + i) * 3 + 0], m[3][i], y3);
            y3 = fmaf(c3w[(o * 50 + i) * 3 + 1], m[4][i], y3);
            y3 = fmaf(c3w[(o * 50 + i) * 3 + 2], m[5][i], y3);
        }
        r[o] = (tanh_fast(y1) + tanh_fast(y2) + tanh_fast(y3)) * (1.f / 3.f);
    }
    __syncthreads();

    // Stage 5: gate input projections. g=0..5 = {fi,ff,fg,bi,bf,bg}.
    // Fwd gates land at step s, bwd gates at step 63-s.
    if (tid < 300) {
        const int g = tid / 50, o = tid - g * 50;
        const float* Wg = (g == 0) ? fiw : (g == 1) ? ffw : (g == 2) ? fgw
                        : (g == 3) ? biw : (g == 4) ? bfw : bgw;
        const float* Bg = (g == 0) ? fib : (g == 1) ? ffb : (g == 2) ? fgb
                        : (g == 3) ? bib : (g == 4) ? bfb : bgb;
        const int sp = (g < 3) ? s : (63 - s);
        const float2* wrow = (const float2*)(Wg + o * 100);   // W[o, 0:50]
        float acc = Bg[o];
#pragma unroll
        for (int j2 = 0; j2 < 25; ++j2) {
            float2 wv = wrow[j2];
            acc = fmaf(wv.x, r[2 * j2], fmaf(wv.y, r[2 * j2 + 1], acc));
        }
        preW[g * 3200 + sp * 50 + o] = acc;
    }
}

// ---------------- Kernel 2: serial bidirectional scan + output --------------
// 1 block, 384 threads = 6 waves. Wave wv = direction*3 + gate.
// Each lane holds only its gate's 50 recurrent weights (no spill).
__global__ __launch_bounds__(384, 1) void scan_kernel(
    const float* __restrict__ preW,      // [6][64][50]
    const float* __restrict__ fiw, const float* __restrict__ ffw,
    const float* __restrict__ fgw, const float* __restrict__ biw,
    const float* __restrict__ bfw, const float* __restrict__ bgw,
    const float* __restrict__ out_w, const float* __restrict__ out_b,
    float* __restrict__ outp)
{
    __shared__ float aL[2][6][50];       // double-buffered gate pre-activations
    __shared__ float mh[2][50];          // mean h per direction
    __shared__ float lg[5];              // logits

    const int tid = threadIdx.x;
    const int wv = tid >> 6, lane = tid & 63;
    const int oc = (lane < 50) ? lane : 0;     // shadow lanes mirror lane 0
    const int d  = (wv >= 3) ? 1 : 0;

    const float* Wg = (wv == 0) ? fiw : (wv == 1) ? ffw : (wv == 2) ? fgw
                    : (wv == 3) ? biw : (wv == 4) ? bfw : bgw;

    // Recurrent weights W[oc, 50+j], j=0..49 -> 50 VGPRs.
    float w[50];
    {
        const float2* wrow = (const float2*)(Wg + oc * 100 + 50);
#pragma unroll
        for (int j2 = 0; j2 < 25; ++j2) {
            float2 t = wrow[j2];
            w[2 * j2] = t.x; w[2 * j2 + 1] = t.y;
        }
    }
    const float* pg = preW + wv * 3200;

    float h = 0.f, hsum = 0.f;
    float na = pg[oc];
#pragma unroll 1
    for (int s2 = 0; s2 < 64; ++s2) {
        // 4 independent accumulator chains over the 50 readlane-FMAs.
        float a0 = na, a1 = 0.f, a2 = 0.f, a3 = 0.f;
        if (s2 < 63) na = pg[(s2 + 1) * 50 + oc];       // prefetch next step
#pragma unroll
        for (int j = 0; j < 48; j += 4) {
            a0 = fmaf(w[j    ], rl(h, j    ), a0);
            a1 = fmaf(w[j + 1], rl(h, j + 1), a1);
            a2 = fmaf(w[j + 2], rl(h, j + 2), a2);
            a3 = fmaf(w[j + 3], rl(h, j + 3), a3);
        }
        a0 = fmaf(w[48], rl(h, 48), a0);
        a1 = fmaf(w[49], rl(h, 49), a1);
        const float a = (a0 + a1) + (a2 + a3);

        if (lane < 50) aL[s2 & 1][wv][lane] = a;
        __syncthreads();                                 // single barrier/step
        const float ai = aL[s2 & 1][d * 3 + 0][oc];
        const float af = aL[s2 & 1][d * 3 + 1][oc];
        const float ag = aL[s2 & 1][d * 3 + 2][oc];
        // All 3 waves of a direction compute identical h (bitwise): same
        // inputs, same instruction sequence -> readlane stays consistent.
        h = tanh_fast(fmaf(sigm(ai), tanh_fast(ag), sigm(af) * h));
        hsum += h;
    }
    if ((wv == 0 || wv == 3) && lane < 50) mh[d][lane] = hsum * (1.f / 64.f);
    __syncthreads();

    // Output layer: 5 logits in parallel, then softmax on thread 0.
    if (tid < 5) {
        const float2* wrow = (const float2*)(out_w + tid * 100);
        float acc = out_b[tid];
#pragma unroll
        for (int j2 = 0; j2 < 25; ++j2) {
            float2 wv2 = wrow[j2];
            acc = fmaf(wv2.x, mh[0][2 * j2], fmaf(wv2.y, mh[0][2 * j2 + 1], acc));
        }
#pragma unroll
        for (int j2 = 0; j2 < 25; ++j2) {
            float2 wv2 = wrow[25 + j2];
            acc = fmaf(wv2.x, mh[1][2 * j2], fmaf(wv2.y, mh[1][2 * j2 + 1], acc));
        }
        lg[tid] = acc;
    }
    __syncthreads();
    if (tid == 0) {
        float mx = lg[0];
#pragma unroll
        for (int k = 1; k < 5; ++k) mx = fmaxf(mx, lg[k]);
        float e[5], se = 0.f;
#pragma unroll
        for (int k = 0; k < 5; ++k) { e[k] = __expf(lg[k] - mx); se += e[k]; }
        const float inv = 1.f / se;
#pragma unroll
        for (int k = 0; k < 5; ++k) outp[k] = e[k] * inv;
    }
}

extern "C" void kernel_launch(void* const* d_in, const int* in_sizes, int n_in,
                              void* d_out, int out_size, void* d_ws, size_t ws_size,
                              hipStream_t stream)
{
    (void)in_sizes; (void)n_in; (void)out_size; (void)ws_size;
    const int*   doc  = (const int*)  d_in[0];
    const float* emb  = (const float*)d_in[1];
    const float* wl_w = (const float*)d_in[2];
    const float* wl_b = (const float*)d_in[3];
    const float* c1w  = (const float*)d_in[4];
    const float* c1b  = (const float*)d_in[5];
    const float* c2w  = (const float*)d_in[6];
    const float* c2b  = (const float*)d_in[7];
    const float* c3w  = (const float*)d_in[8];
    const float* c3b  = (const float*)d_in[9];
    const float* fiw  = (const float*)d_in[10];
    const float* fib  = (const float*)d_in[11];
    const float* ffw  = (const float*)d_in[12];
    const float* ffb  = (const float*)d_in[13];
    const float* fgw  = (const float*)d_in[14];
    const float* fgb  = (const float*)d_in[15];
    const float* biw  = (const float*)d_in[16];
    const float* bib  = (const float*)d_in[17];
    const float* bfw  = (const float*)d_in[18];
    const float* bfb  = (const float*)d_in[19];
    const float* bgw  = (const float*)d_in[20];
    const float* bgb  = (const float*)d_in[21];
    const float* ow   = (const float*)d_in[22];
    const float* ob   = (const float*)d_in[23];

    float* preW = (float*)d_ws;          // 6*64*50 floats

    rep_kernel<<<64, 320, 0, stream>>>(doc, emb, wl_w, wl_b,
                                       c1w, c1b, c2w, c2b, c3w, c3b,
                                       fiw, fib, ffw, ffb, fgw, fgb,
                                       biw, bib, bfw, bfb, bgw, bgb, preW);
    scan_kernel<<<1, 384, 0, stream>>>(preW, fiw, ffw, fgw, biw, bfw, bgw,
                                       ow, ob, (float*)d_out);
}

// Round 5
// 266.817 us; speedup vs baseline: 1.3724x; 1.0035x over previous
//
#include <hip/hip_runtime.h>

// GRNN fused implementation. VOCAB=100000, D=300, H=50, S=64, W=32, OUT=5.
// All fp32 in/out (established rounds 0-3).
//
// Round-5 change: round-4's scan step kept a GLOBAL prefetch of preW inside
// the serial loop; preW lines were written by 64 blocks across 8 XCDs, so the
// load ran at L3/cross-XCD latency (~700 cyc) and __syncthreads' vmcnt(0)
// drain serialized it into every step -> ~2200 cyc/step, ~60 us. Now preW is
// staged into LDS once (76.8 KB, coalesced) and the 64-step loop touches only
// LDS+VALU: ds_read prefetch + readlane matvec + 1 barrier/step.
//
// Algebra: conv branches only need window-means over w of p = x@wl^T + b;
// all 6 windows derive from colsum(x) minus edge rows x0,x1,x30,x31 -> 5
// matvecs (50x300) per sentence instead of a 32x50x300 matmul. h_b reversal
// before the mean is a no-op (mean over steps), so the bwd scan just consumes
// rep in reverse order via the projection indexing in rep_kernel stage 5.

__device__ __forceinline__ float rl(float v, int j) {
    return __uint_as_float((unsigned)__builtin_amdgcn_readlane(__float_as_uint(v), j));
}
__device__ __forceinline__ float sigm(float x) { return 1.f / (1.f + __expf(-x)); }
__device__ __forceinline__ float tanh_fast(float x) {
    return 1.f - 2.f / (__expf(2.f * x) + 1.f);   // exact at +-inf, ~1e-7 abs err
}

// ---------------- Kernel 1: rep + gate input-projections --------------------
// One block per sentence s, 320 threads (5 waves).
__global__ __launch_bounds__(320, 1) void rep_kernel(
    const int* __restrict__ doc, const float* __restrict__ emb,
    const float* __restrict__ wl_w, const float* __restrict__ wl_b,
    const float* __restrict__ c1w, const float* __restrict__ c1b,
    const float* __restrict__ c2w, const float* __restrict__ c2b,
    const float* __restrict__ c3w, const float* __restrict__ c3b,
    const float* __restrict__ fiw, const float* __restrict__ fib,
    const float* __restrict__ ffw, const float* __restrict__ ffb,
    const float* __restrict__ fgw, const float* __restrict__ fgb,
    const float* __restrict__ biw, const float* __restrict__ bib,
    const float* __restrict__ bfw, const float* __restrict__ bfb,
    const float* __restrict__ bgw, const float* __restrict__ bgb,
    float* __restrict__ preW)            // [6][64][50]
{
    __shared__ int docs[32];
    __shared__ float xL[32][300];   // gathered embedding rows
    __shared__ float sv[5][300];    // [colsum, x0, x1, x30, x31]
    __shared__ float P[5][50];      // wl_w @ sv_v
    __shared__ float m[6][50];      // the 6 window means (p-space)
    __shared__ float r[50];         // rep[s]

    const int s = blockIdx.x, tid = threadIdx.x;
    if (tid < 32) docs[tid] = doc[s * 32 + tid];
    __syncthreads();

    // Stage 1: gather 32 rows x 300 fp32. 10 threads/row, 15 float2 each.
    {
        const int w = tid / 10, part = tid - w * 10;
        const float2* row = (const float2*)(emb + docs[w] * 300);
#pragma unroll
        for (int t = 0; t < 15; ++t) {
            float2 v = row[part * 15 + t];
            const int d = (part * 15 + t) * 2;
            xL[w][d]     = v.x;
            xL[w][d + 1] = v.y;
        }
    }
    __syncthreads();

    // Stage 1b: column sums + edge rows.
    if (tid < 300) {
        float a = 0.f;
#pragma unroll
        for (int w = 0; w < 32; ++w) a += xL[w][tid];
        sv[0][tid] = a;
        sv[1][tid] = xL[0][tid];
        sv[2][tid] = xL[1][tid];
        sv[3][tid] = xL[30][tid];
        sv[4][tid] = xL[31][tid];
    }
    __syncthreads();

    // Stage 2: P[v][i] = wl_w[i,:] . sv[v,:]
    if (tid < 250) {
        const int i = tid / 5, v = tid - (tid / 5) * 5;
        const float2* wrow = (const float2*)(wl_w + i * 300);
        float a0 = 0.f, a1 = 0.f;
#pragma unroll 5
        for (int d2 = 0; d2 < 150; ++d2) {
            float2 wv = wrow[d2];
            a0 = fmaf(wv.x, sv[v][2 * d2],     a0);
            a1 = fmaf(wv.y, sv[v][2 * d2 + 1], a1);
        }
        P[v][i] = a0 + a1;
    }
    __syncthreads();

    // Stage 3: the 6 window means. mean = Qwin/len + wl_b.
    if (tid < 50) {
        const int i = tid;
        const float b  = wl_b[i];
        const float QA = P[0][i], Q0 = P[1][i], Q1 = P[2][i],
                    Q30 = P[3][i], Q31 = P[4][i];
        m[0][i] = QA * (1.f / 32.f) + b;
        m[1][i] = (QA - Q31) * (1.f / 31.f) + b;
        m[2][i] = (QA - Q0)  * (1.f / 31.f) + b;
        m[3][i] = (QA - Q30 - Q31) * (1.f / 30.f) + b;
        m[4][i] = (QA - Q0  - Q31) * (1.f / 30.f) + b;
        m[5][i] = (QA - Q0  - Q1 ) * (1.f / 30.f) + b;
    }
    __syncthreads();

    // Stage 4: conv branches + tanh + average -> r[o].
    if (tid < 50) {
        const int o = tid;
        float y1 = c1b[o], y2 = c2b[o], y3 = c3b[o];
        for (int i = 0; i < 50; ++i) {
            y1 = fmaf(c1w[o * 50 + i], m[0][i], y1);
            const float2 w2 = ((const float2*)c2w)[o * 50 + i];
            y2 = fmaf(w2.x, m[1][i], fmaf(w2.y, m[2][i], y2));
            y3 = fmaf(c3w[(o * 50 + i) * 3 + 0], m[3][i], y3);
            y3 = fmaf(c3w[(o * 50 + i) * 3 + 1], m[4][i], y3);
            y3 = fmaf(c3w[(o * 50 + i) * 3 + 2], m[5][i], y3);
        }
        r[o] = (tanh_fast(y1) + tanh_fast(y2) + tanh_fast(y3)) * (1.f / 3.f);
    }
    __syncthreads();

    // Stage 5: gate input projections. g=0..5 = {fi,ff,fg,bi,bf,bg}.
    // Fwd gates land at step s, bwd gates at step 63-s.
    if (tid < 300) {
        const int g = tid / 50, o = tid - g * 50;
        const float* Wg = (g == 0) ? fiw : (g == 1) ? ffw : (g == 2) ? fgw
                        : (g == 3) ? biw : (g == 4) ? bfw : bgw;
        const float* Bg = (g == 0) ? fib : (g == 1) ? ffb : (g == 2) ? fgb
                        : (g == 3) ? bib : (g == 4) ? bfb : bgb;
        const int sp = (g < 3) ? s : (63 - s);
        const float2* wrow = (const float2*)(Wg + o * 100);   // W[o, 0:50]
        float acc = Bg[o];
#pragma unroll
        for (int j2 = 0; j2 < 25; ++j2) {
            float2 wv = wrow[j2];
            acc = fmaf(wv.x, r[2 * j2], fmaf(wv.y, r[2 * j2 + 1], acc));
        }
        preW[g * 3200 + sp * 50 + o] = acc;
    }
}

// ---------------- Kernel 2: serial bidirectional scan + output --------------
// 1 block, 384 threads = 6 waves. Wave wv = direction*3 + gate.
// Each lane holds only its gate's 50 recurrent weights (no spill).
// preW staged into LDS up-front -> zero global ops in the 64-step loop.
__global__ __launch_bounds__(384, 1) void scan_kernel(
    const float* __restrict__ preW,      // [6][64][50]
    const float* __restrict__ fiw, const float* __restrict__ ffw,
    const float* __restrict__ fgw, const float* __restrict__ biw,
    const float* __restrict__ bfw, const float* __restrict__ bgw,
    const float* __restrict__ out_w, const float* __restrict__ out_b,
    float* __restrict__ outp)
{
    __shared__ float pre[6][64][50];     // 76.8 KB staged pre-activations
    __shared__ float aL[2][6][52];       // double-buffered gate pre-acts
    __shared__ float mh[2][52];          // mean h per direction
    __shared__ float lg[5];              // logits

    const int tid = threadIdx.x;
    const int wv = tid >> 6, lane = tid & 63;
    const int oc = (lane < 50) ? lane : 0;     // shadow lanes mirror lane 0
    const int d  = (wv >= 3) ? 1 : 0;

    // Stage preW -> LDS, coalesced float2: 9600 pairs / 384 threads = 25 each.
    {
        const float2* src = (const float2*)preW;
        float2* dst = (float2*)&pre[0][0][0];
#pragma unroll
        for (int k = 0; k < 25; ++k) dst[tid + 384 * k] = src[tid + 384 * k];
    }

    // Recurrent weights W[oc, 50+j], j=0..49 -> 50 VGPRs (issued while the
    // LDS staging is in flight; both drained by the first __syncthreads).
    const float* Wg = (wv == 0) ? fiw : (wv == 1) ? ffw : (wv == 2) ? fgw
                    : (wv == 3) ? biw : (wv == 4) ? bfw : bgw;
    float w[50];
    {
        const float2* wrow = (const float2*)(Wg + oc * 100 + 50);
#pragma unroll
        for (int j2 = 0; j2 < 25; ++j2) {
            float2 t = wrow[j2];
            w[2 * j2] = t.x; w[2 * j2 + 1] = t.y;
        }
    }
    __syncthreads();

    float h = 0.f, hsum = 0.f;
    float na = pre[wv][0][oc];
#pragma unroll 1
    for (int s2 = 0; s2 < 64; ++s2) {
        // 4 independent accumulator chains over the 50 readlane-FMAs.
        float a0 = na, a1 = 0.f, a2 = 0.f, a3 = 0.f;
        if (s2 < 63) na = pre[wv][s2 + 1][oc];   // ds_read, hidden by matvec
#pragma unroll
        for (int j = 0; j < 48; j += 4) {
            a0 = fmaf(w[j    ], rl(h, j    ), a0);
            a1 = fmaf(w[j + 1], rl(h, j + 1), a1);
            a2 = fmaf(w[j + 2], rl(h, j + 2), a2);
            a3 = fmaf(w[j + 3], rl(h, j + 3), a3);
        }
        a0 = fmaf(w[48], rl(h, 48), a0);
        a1 = fmaf(w[49], rl(h, 49), a1);
        const float a = (a0 + a1) + (a2 + a3);

        if (lane < 50) aL[s2 & 1][wv][lane] = a;
        __syncthreads();                          // drains only LDS ops now
        const float ai = aL[s2 & 1][d * 3 + 0][oc];
        const float af = aL[s2 & 1][d * 3 + 1][oc];
        const float ag = aL[s2 & 1][d * 3 + 2][oc];
        // All 3 waves of a direction compute identical h: same inputs, same
        // instruction sequence -> each wave's readlane view stays correct.
        h = tanh_fast(fmaf(sigm(ai), tanh_fast(ag), sigm(af) * h));
        hsum += h;
    }
    if ((wv == 0 || wv == 3) && lane < 50) mh[d][lane] = hsum * (1.f / 64.f);
    __syncthreads();

    // Output layer: 5 logits in parallel, then softmax on thread 0.
    if (tid < 5) {
        const float2* wrow = (const float2*)(out_w + tid * 100);
        float acc = out_b[tid];
#pragma unroll
        for (int j2 = 0; j2 < 25; ++j2) {
            float2 wv2 = wrow[j2];
            acc = fmaf(wv2.x, mh[0][2 * j2], fmaf(wv2.y, mh[0][2 * j2 + 1], acc));
        }
#pragma unroll
        for (int j2 = 0; j2 < 25; ++j2) {
            float2 wv2 = wrow[25 + j2];
            acc = fmaf(wv2.x, mh[1][2 * j2], fmaf(wv2.y, mh[1][2 * j2 + 1], acc));
        }
        lg[tid] = acc;
    }
    __syncthreads();
    if (tid == 0) {
        float mx = lg[0];
#pragma unroll
        for (int k = 1; k < 5; ++k) mx = fmaxf(mx, lg[k]);
        float e[5], se = 0.f;
#pragma unroll
        for (int k = 0; k < 5; ++k) { e[k] = __expf(lg[k] - mx); se += e[k]; }
        const float inv = 1.f / se;
#pragma unroll
        for (int k = 0; k < 5; ++k) outp[k] = e[k] * inv;
    }
}

extern "C" void kernel_launch(void* const* d_in, const int* in_sizes, int n_in,
                              void* d_out, int out_size, void* d_ws, size_t ws_size,
                              hipStream_t stream)
{
    (void)in_sizes; (void)n_in; (void)out_size; (void)ws_size;
    const int*   doc  = (const int*)  d_in[0];
    const float* emb  = (const float*)d_in[1];
    const float* wl_w = (const float*)d_in[2];
    const float* wl_b = (const float*)d_in[3];
    const float* c1w  = (const float*)d_in[4];
    const float* c1b  = (const float*)d_in[5];
    const float* c2w  = (const float*)d_in[6];
    const float* c2b  = (const float*)d_in[7];
    const float* c3w  = (const float*)d_in[8];
    const float* c3b  = (const float*)d_in[9];
    const float* fiw  = (const float*)d_in[10];
    const float* fib  = (const float*)d_in[11];
    const float* ffw  = (const float*)d_in[12];
    const float* ffb  = (const float*)d_in[13];
    const float* fgw  = (const float*)d_in[14];
    const float* fgb  = (const float*)d_in[15];
    const float* biw  = (const float*)d_in[16];
    const float* bib  = (const float*)d_in[17];
    const float* bfw  = (const float*)d_in[18];
    const float* bfb  = (const float*)d_in[19];
    const float* bgw  = (const float*)d_in[20];
    const float* bgb  = (const float*)d_in[21];
    const float* ow   = (const float*)d_in[22];
    const float* ob   = (const float*)d_in[23];

    float* preW = (float*)d_ws;          // 6*64*50 floats

    rep_kernel<<<64, 320, 0, stream>>>(doc, emb, wl_w, wl_b,
                                       c1w, c1b, c2w, c2b, c3w, c3b,
                                       fiw, fib, ffw, ffb, fgw, fgb,
                                       biw, bib, bfw, bfb, bgw, bgb, preW);
    scan_kernel<<<1, 384, 0, stream>>>(preW, fiw, ffw, fgw, biw, bfw, bgw,
                                       ow, ob, (float*)d_out);
}

// Round 6
// 258.821 us; speedup vs baseline: 1.4148x; 1.0309x over previous
//
#include <hip/hip_runtime.h>
#include <hip/hip_fp16.h>

// GRNN fused implementation. VOCAB=100000, D=300, H=50, S=64, W=32, OUT=5.
// All fp32 in/out (established rounds 0-3).
//
// Round-6: cross-round arithmetic shows scan ~60us regardless of r5's LDS
// staging -> the cost is the loop body itself (6 waves: barrier + LDS
// exchange + 2-waves/SIMD issue contention, at low DVFS clocks). New scan:
// ONE wave per direction, zero barriers/LDS in the 64-step loop. Each lane
// holds all 150 recurrent weights as 75 packed fp16 half2 (no spill; fp32
// accumulate; mad-mix foldable). rep_kernel: stage-4 parallelized to 300
// threads; stage-1 gather via float4 (emb rows 16B-aligned: 1200B stride).
//
// Algebra: conv branches only need window-means over w of p = x@wl^T + b;
// all 6 windows derive from colsum(x) minus edge rows x0,x1,x30,x31 -> 5
// matvecs (50x300) per sentence instead of a 32x50x300 matmul. h_b reversal
// before the mean is a no-op (mean over steps), so the bwd scan consumes rep
// reversed via projection indexing in rep_kernel stage 5.

__device__ __forceinline__ float rl(float v, int j) {
    return __uint_as_float((unsigned)__builtin_amdgcn_readlane(__float_as_uint(v), j));
}
__device__ __forceinline__ float sigm(float x) { return 1.f / (1.f + __expf(-x)); }
__device__ __forceinline__ float tanh_fast(float x) {
    return 1.f - 2.f / (__expf(2.f * x) + 1.f);   // exact at +-inf, ~1e-7 abs err
}

// ---------------- Kernel 1: rep + gate input-projections --------------------
// One block per sentence s, 320 threads (5 waves).
__global__ __launch_bounds__(320, 1) void rep_kernel(
    const int* __restrict__ doc, const float* __restrict__ emb,
    const float* __restrict__ wl_w, const float* __restrict__ wl_b,
    const float* __restrict__ c1w, const float* __restrict__ c1b,
    const float* __restrict__ c2w, const float* __restrict__ c2b,
    const float* __restrict__ c3w, const float* __restrict__ c3b,
    const float* __restrict__ fiw, const float* __restrict__ fib,
    const float* __restrict__ ffw, const float* __restrict__ ffb,
    const float* __restrict__ fgw, const float* __restrict__ fgb,
    const float* __restrict__ biw, const float* __restrict__ bib,
    const float* __restrict__ bfw, const float* __restrict__ bfb,
    const float* __restrict__ bgw, const float* __restrict__ bgb,
    float* __restrict__ preW)            // [6][64][50]
{
    __shared__ int docs[32];
    __shared__ float xL[32][300];   // gathered embedding rows
    __shared__ float sv[5][300];    // [colsum, x0, x1, x30, x31]
    __shared__ float P[5][50];      // wl_w @ sv_v
    __shared__ float m[6][50];      // the 6 window means (p-space)
    __shared__ float part[6][50];   // stage-4 partial dots
    __shared__ float r[50];         // rep[s]

    const int s = blockIdx.x, tid = threadIdx.x;
    if (tid < 32) docs[tid] = doc[s * 32 + tid];
    __syncthreads();

    // Stage 1: gather 32 rows x 300 fp32 via float4 (rows 16B-aligned).
    {
        const float4* ef4 = (const float4*)emb;   // row r = docs[r]*75 float4s
        float4* xf4 = (float4*)&xL[0][0];         // xL flat: idx = r*75 + c
        for (int idx = tid; idx < 2400; idx += 320) {
            const int rr = idx / 75, c = idx - rr * 75;
            xf4[idx] = ef4[docs[rr] * 75 + c];
        }
    }
    __syncthreads();

    // Stage 1b: column sums + edge rows.
    if (tid < 300) {
        float a = 0.f;
#pragma unroll
        for (int w = 0; w < 32; ++w) a += xL[w][tid];
        sv[0][tid] = a;
        sv[1][tid] = xL[0][tid];
        sv[2][tid] = xL[1][tid];
        sv[3][tid] = xL[30][tid];
        sv[4][tid] = xL[31][tid];
    }
    __syncthreads();

    // Stage 2: P[v][i] = wl_w[i,:] . sv[v,:]
    if (tid < 250) {
        const int i = tid / 5, v = tid - (tid / 5) * 5;
        const float2* wrow = (const float2*)(wl_w + i * 300);
        float a0 = 0.f, a1 = 0.f;
#pragma unroll 5
        for (int d2 = 0; d2 < 150; ++d2) {
            float2 wv = wrow[d2];
            a0 = fmaf(wv.x, sv[v][2 * d2],     a0);
            a1 = fmaf(wv.y, sv[v][2 * d2 + 1], a1);
        }
        P[v][i] = a0 + a1;
    }
    __syncthreads();

    // Stage 3: the 6 window means. mean = Qwin/len + wl_b.
    if (tid < 50) {
        const int i = tid;
        const float b  = wl_b[i];
        const float QA = P[0][i], Q0 = P[1][i], Q1 = P[2][i],
                    Q30 = P[3][i], Q31 = P[4][i];
        m[0][i] = QA * (1.f / 32.f) + b;
        m[1][i] = (QA - Q31) * (1.f / 31.f) + b;
        m[2][i] = (QA - Q0)  * (1.f / 31.f) + b;
        m[3][i] = (QA - Q30 - Q31) * (1.f / 30.f) + b;
        m[4][i] = (QA - Q0  - Q31) * (1.f / 30.f) + b;
        m[5][i] = (QA - Q0  - Q1 ) * (1.f / 30.f) + b;
    }
    __syncthreads();

    // Stage 4: 6 parallel partial dots (q = branch/window slice, o = output).
    // Uniform loop body (selects via cndmask, no divergent code paths).
    if (tid < 300) {
        const int q = tid / 50, o = tid - q * 50;
        const float* base = (q == 0) ? c1w : (q < 3) ? c2w : c3w;
        const int str = (q == 0) ? 1 : (q < 3) ? 2 : 3;
        const int off = (q == 0) ? 0 : (q < 3) ? (q - 1) : (q - 3);
        float acc = (q == 0) ? c1b[o] : (q == 1) ? c2b[o] : (q == 3) ? c3b[o] : 0.f;
        const float* mp = m[q];
#pragma unroll 5
        for (int i = 0; i < 50; ++i)
            acc = fmaf(base[(o * 50 + i) * str + off], mp[i], acc);
        part[q][o] = acc;
    }
    __syncthreads();
    if (tid < 50) {
        const float y1 = tanh_fast(part[0][tid]);
        const float y2 = tanh_fast(part[1][tid] + part[2][tid]);
        const float y3 = tanh_fast(part[3][tid] + part[4][tid] + part[5][tid]);
        r[tid] = (y1 + y2 + y3) * (1.f / 3.f);
    }
    __syncthreads();

    // Stage 5: gate input projections. g=0..5 = {fi,ff,fg,bi,bf,bg}.
    // Fwd gates land at step s, bwd gates at step 63-s.
    if (tid < 300) {
        const int g = tid / 50, o = tid - g * 50;
        const float* Wg = (g == 0) ? fiw : (g == 1) ? ffw : (g == 2) ? fgw
                        : (g == 3) ? biw : (g == 4) ? bfw : bgw;
        const float* Bg = (g == 0) ? fib : (g == 1) ? ffb : (g == 2) ? fgb
                        : (g == 3) ? bib : (g == 4) ? bfb : bgb;
        const int sp = (g < 3) ? s : (63 - s);
        const float2* wrow = (const float2*)(Wg + o * 100);   // W[o, 0:50]
        float acc = Bg[o];
#pragma unroll
        for (int j2 = 0; j2 < 25; ++j2) {
            float2 wv = wrow[j2];
            acc = fmaf(wv.x, r[2 * j2], fmaf(wv.y, r[2 * j2 + 1], acc));
        }
        preW[g * 3200 + sp * 50 + o] = acc;
    }
}

// ---------------- Kernel 2: serial bidirectional scan + output --------------
// 1 block, 128 threads = 2 fully independent waves (wave = direction).
// Lane o holds ALL 3 gates' recurrent weights as 75 packed fp16 half2 ->
// no spill, no barrier, no LDS in the 64-step loop. fp32 accumulation.
__global__ __launch_bounds__(128, 1) void scan_kernel(
    const float* __restrict__ preW,      // [6][64][50]
    const float* __restrict__ fiw, const float* __restrict__ ffw,
    const float* __restrict__ fgw, const float* __restrict__ biw,
    const float* __restrict__ bfw, const float* __restrict__ bgw,
    const float* __restrict__ out_w, const float* __restrict__ out_b,
    float* __restrict__ outp)
{
    __shared__ float pre[6][64][50];     // 76.8 KB staged pre-activations
    __shared__ float mh[2][52];          // mean h per direction
    __shared__ float lg[5];              // logits

    const int tid = threadIdx.x;
    const int d = tid >> 6, lane = tid & 63;
    const int oc = (lane < 50) ? lane : 0;     // shadow lanes mirror lane 0

    // Stage preW -> LDS, coalesced float2: 9600 pairs / 128 threads = 75 each.
    {
        const float2* src = (const float2*)preW;
        float2* dst = (float2*)&pre[0][0][0];
#pragma unroll
        for (int k = 0; k < 75; ++k) dst[tid + 128 * k] = src[tid + 128 * k];
    }

    // Recurrent weights W[oc, 50+j] for the 3 gates -> fp16 half2 x 25 each.
    const float* Wi = d ? biw : fiw;
    const float* Wf = d ? bfw : ffw;
    const float* Wg = d ? bgw : fgw;
    __half2 hwi[25], hwf[25], hwg[25];
    {
        const float2* ri = (const float2*)(Wi + oc * 100 + 50);
        const float2* rf = (const float2*)(Wf + oc * 100 + 50);
        const float2* rg = (const float2*)(Wg + oc * 100 + 50);
#pragma unroll
        for (int k = 0; k < 25; ++k) {
            float2 a = ri[k], b = rf[k], c = rg[k];
            hwi[k] = __floats2half2_rn(a.x, a.y);
            hwf[k] = __floats2half2_rn(b.x, b.y);
            hwg[k] = __floats2half2_rn(c.x, c.y);
        }
    }
    __syncthreads();    // pre[] staged; waves are independent from here on

    const int g0 = d * 3;
    float h = 0.f, hsum = 0.f;
    float nai = pre[g0 + 0][0][oc];
    float naf = pre[g0 + 1][0][oc];
    float nag = pre[g0 + 2][0][oc];
#pragma unroll 1
    for (int s2 = 0; s2 < 64; ++s2) {
        float ai = nai, af = naf, ag = nag;
        if (s2 < 63) {                          // ds_read, hidden by matvec
            nai = pre[g0 + 0][s2 + 1][oc];
            naf = pre[g0 + 1][s2 + 1][oc];
            nag = pre[g0 + 2][s2 + 1][oc];
        }
        // 3 independent chains x 2 fma per k; h broadcast via readlane SGPR.
#pragma unroll
        for (int k = 0; k < 25; ++k) {
            const float h0 = rl(h, 2 * k);
            const float h1 = rl(h, 2 * k + 1);
            ai = fmaf(__low2float(hwi[k]), h0, fmaf(__high2float(hwi[k]), h1, ai));
            af = fmaf(__low2float(hwf[k]), h0, fmaf(__high2float(hwf[k]), h1, af));
            ag = fmaf(__low2float(hwg[k]), h0, fmaf(__high2float(hwg[k]), h1, ag));
        }
        h = tanh_fast(fmaf(sigm(ai), tanh_fast(ag), sigm(af) * h));
        hsum += h;
    }
    if (lane < 50) mh[d][lane] = hsum * (1.f / 64.f);
    __syncthreads();

    // Output layer: 5 logits in parallel, then softmax on thread 0.
    if (tid < 5) {
        const float2* wrow = (const float2*)(out_w + tid * 100);
        float acc = out_b[tid];
#pragma unroll
        for (int j2 = 0; j2 < 25; ++j2) {
            float2 wv2 = wrow[j2];
            acc = fmaf(wv2.x, mh[0][2 * j2], fmaf(wv2.y, mh[0][2 * j2 + 1], acc));
        }
#pragma unroll
        for (int j2 = 0; j2 < 25; ++j2) {
            float2 wv2 = wrow[25 + j2];
            acc = fmaf(wv2.x, mh[1][2 * j2], fmaf(wv2.y, mh[1][2 * j2 + 1], acc));
        }
        lg[tid] = acc;
    }
    __syncthreads();
    if (tid == 0) {
        float mx = lg[0];
#pragma unroll
        for (int k = 1; k < 5; ++k) mx = fmaxf(mx, lg[k]);
        float e[5], se = 0.f;
#pragma unroll
        for (int k = 0; k < 5; ++k) { e[k] = __expf(lg[k] - mx); se += e[k]; }
        const float inv = 1.f / se;
#pragma unroll
        for (int k = 0; k < 5; ++k) outp[k] = e[k] * inv;
    }
}

extern "C" void kernel_launch(void* const* d_in, const int* in_sizes, int n_in,
                              void* d_out, int out_size, void* d_ws, size_t ws_size,
                              hipStream_t stream)
{
    (void)in_sizes; (void)n_in; (void)out_size; (void)ws_size;
    const int*   doc  = (const int*)  d_in[0];
    const float* emb  = (const float*)d_in[1];
    const float* wl_w = (const float*)d_in[2];
    const float* wl_b = (const float*)d_in[3];
    const float* c1w  = (const float*)d_in[4];
    const float* c1b  = (const float*)d_in[5];
    const float* c2w  = (const float*)d_in[6];
    const float* c2b  = (const float*)d_in[7];
    const float* c3w  = (const float*)d_in[8];
    const float* c3b  = (const float*)d_in[9];
    const float* fiw  = (const float*)d_in[10];
    const float* fib  = (const float*)d_in[11];
    const float* ffw  = (const float*)d_in[12];
    const float* ffb  = (const float*)d_in[13];
    const float* fgw  = (const float*)d_in[14];
    const float* fgb  = (const float*)d_in[15];
    const float* biw  = (const float*)d_in[16];
    const float* bib  = (const float*)d_in[17];
    const float* bfw  = (const float*)d_in[18];
    const float* bfb  = (const float*)d_in[19];
    const float* bgw  = (const float*)d_in[20];
    const float* bgb  = (const float*)d_in[21];
    const float* ow   = (const float*)d_in[22];
    const float* ob   = (const float*)d_in[23];

    float* preW = (float*)d_ws;          // 6*64*50 floats

    rep_kernel<<<64, 320, 0, stream>>>(doc, emb, wl_w, wl_b,
                                       c1w, c1b, c2w, c2b, c3w, c3b,
                                       fiw, fib, ffw, ffb, fgw, fgb,
                                       biw, bib, bfw, bfb, bgw, bgb, preW);
    scan_kernel<<<1, 128, 0, stream>>>(preW, fiw, ffw, fgw, biw, bfw, bgw,
                                       ow, ob, (float*)d_out);
}

// Round 7
// 244.056 us; speedup vs baseline: 1.5004x; 1.0605x over previous
//
#include <hip/hip_runtime.h>
#include <hip/hip_fp16.h>

// GRNN fused implementation. VOCAB=100000, D=300, H=50, S=64, W=32, OUT=5.
// All fp32 in/out (established rounds 0-3).
//
// Round-7: scan is frozen at its serial floor (~400 cyc/step x 64 steps at
// DVFS-throttled clocks; r5/r6 structural changes each bought ~15%). This
// round attacks rep_kernel's latency chains: wl_w staged to LDS (stage-2
// inner loop becomes LDS+FMA instead of 150 L2-latency loads at unroll-5),
// 512 threads with stage-2 split into 500 half-dots, stage-4 full unroll.
//
// Algebra: conv branches only need window-means over w of p = x@wl^T + b;
// all 6 windows derive from colsum(x) minus edge rows x0,x1,x30,x31 -> 5
// matvecs (50x300) per sentence instead of a 32x50x300 matmul. h_b reversal
// before the mean is a no-op (mean over steps), so the bwd scan consumes rep
// reversed via projection indexing in rep_kernel stage 5.

__device__ __forceinline__ float rl(float v, int j) {
    return __uint_as_float((unsigned)__builtin_amdgcn_readlane(__float_as_uint(v), j));
}
__device__ __forceinline__ float sigm(float x) { return 1.f / (1.f + __expf(-x)); }
__device__ __forceinline__ float tanh_fast(float x) {
    return 1.f - 2.f / (__expf(2.f * x) + 1.f);   // exact at +-inf, ~1e-7 abs err
}

// ---------------- Kernel 1: rep + gate input-projections --------------------
// One block per sentence s, 512 threads (8 waves).
__global__ __launch_bounds__(512, 1) void rep_kernel(
    const int* __restrict__ doc, const float* __restrict__ emb,
    const float* __restrict__ wl_w, const float* __restrict__ wl_b,
    const float* __restrict__ c1w, const float* __restrict__ c1b,
    const float* __restrict__ c2w, const float* __restrict__ c2b,
    const float* __restrict__ c3w, const float* __restrict__ c3b,
    const float* __restrict__ fiw, const float* __restrict__ fib,
    const float* __restrict__ ffw, const float* __restrict__ ffb,
    const float* __restrict__ fgw, const float* __restrict__ fgb,
    const float* __restrict__ biw, const float* __restrict__ bib,
    const float* __restrict__ bfw, const float* __restrict__ bfb,
    const float* __restrict__ bgw, const float* __restrict__ bgb,
    float* __restrict__ preW)            // [6][64][50]
{
    __shared__ float wlw[15000];    // 60 KB: wl_w staged row-major [50][300]
    __shared__ float xL[32][300];   // 38.4 KB: gathered embedding rows
    __shared__ float sv[5][300];    // [colsum, x0, x1, x30, x31]
    __shared__ float Ph[2][5][52];  // stage-2 half-dots
    __shared__ float m[6][52];      // the 6 window means (p-space)
    __shared__ float part[6][52];   // stage-4 partial dots
    __shared__ float r[52];         // rep[s]
    __shared__ int docs[32];

    const int s = blockIdx.x, tid = threadIdx.x;
    if (tid < 32) docs[tid] = doc[s * 32 + tid];
    __syncthreads();

    // Stage 1: stage wl_w -> LDS (3750 float4) and gather 32 emb rows
    // (2400 float4), all loads independent and coalesced.
    {
        const float4* wsrc = (const float4*)wl_w;
        float4* wdst = (float4*)wlw;
#pragma unroll
        for (int k = 0; k < 8; ++k) {           // 8*512 >= 3750
            const int idx = tid + 512 * k;
            if (idx < 3750) wdst[idx] = wsrc[idx];
        }
        const float4* ef4 = (const float4*)emb; // emb row = 75 float4 (16B-aligned)
        float4* xf4 = (float4*)&xL[0][0];
#pragma unroll
        for (int k = 0; k < 5; ++k) {           // 5*512 >= 2400
            const int idx = tid + 512 * k;
            if (idx < 2400) {
                const int rr = idx / 75, c = idx - rr * 75;
                xf4[idx] = ef4[docs[rr] * 75 + c];
            }
        }
    }
    __syncthreads();

    // Stage 1b: column sums + edge rows.
    if (tid < 300) {
        float a = 0.f;
#pragma unroll
        for (int w = 0; w < 32; ++w) a += xL[w][tid];
        sv[0][tid] = a;
        sv[1][tid] = xL[0][tid];
        sv[2][tid] = xL[1][tid];
        sv[3][tid] = xL[30][tid];
        sv[4][tid] = xL[31][tid];
    }
    __syncthreads();

    // Stage 2: 500 half-dot tasks: Ph[hf][v][i] = wlw[i, hf*150:+150].sv[v,..]
    // Pure LDS + FMA; 75 iters x 2 chains.
    if (tid < 500) {
        const int i = tid / 10, rem = tid - i * 10, v = rem >> 1, hf = rem & 1;
        const float2* w2 = (const float2*)(wlw + i * 300 + hf * 150);
        const float2* x2 = (const float2*)(sv[v] + hf * 150);
        float a0 = 0.f, a1 = 0.f;
#pragma unroll
        for (int k = 0; k < 75; ++k) {
            const float2 w = w2[k], x = x2[k];
            a0 = fmaf(w.x, x.x, a0);
            a1 = fmaf(w.y, x.y, a1);
        }
        Ph[hf][v][i] = a0 + a1;
    }
    __syncthreads();

    // Stage 3: the 6 window means. mean = Qwin/len + wl_b.
    if (tid < 50) {
        const int i = tid;
        const float b   = wl_b[i];
        const float QA  = Ph[0][0][i] + Ph[1][0][i];
        const float Q0  = Ph[0][1][i] + Ph[1][1][i];
        const float Q1  = Ph[0][2][i] + Ph[1][2][i];
        const float Q30 = Ph[0][3][i] + Ph[1][3][i];
        const float Q31 = Ph[0][4][i] + Ph[1][4][i];
        m[0][i] = QA * (1.f / 32.f) + b;
        m[1][i] = (QA - Q31) * (1.f / 31.f) + b;
        m[2][i] = (QA - Q0)  * (1.f / 31.f) + b;
        m[3][i] = (QA - Q30 - Q31) * (1.f / 30.f) + b;
        m[4][i] = (QA - Q0  - Q31) * (1.f / 30.f) + b;
        m[5][i] = (QA - Q0  - Q1 ) * (1.f / 30.f) + b;
    }
    __syncthreads();

    // Stage 4: 6 parallel partial dots, full unroll -> all 50 global loads
    // in flight; 2 accumulator chains.
    if (tid < 300) {
        const int q = tid / 50, o = tid - q * 50;
        const float* base = (q == 0) ? c1w : (q < 3) ? c2w : c3w;
        const int str = (q == 0) ? 1 : (q < 3) ? 2 : 3;
        const int off = (q == 0) ? 0 : (q < 3) ? (q - 1) : (q - 3);
        float a0 = (q == 0) ? c1b[o] : (q == 1) ? c2b[o] : (q == 3) ? c3b[o] : 0.f;
        float a1 = 0.f;
        const float* mp = m[q];
#pragma unroll
        for (int i = 0; i < 50; i += 2) {
            a0 = fmaf(base[(o * 50 + i)     * str + off], mp[i],     a0);
            a1 = fmaf(base[(o * 50 + i + 1) * str + off], mp[i + 1], a1);
        }
        part[q][o] = a0 + a1;
    }
    __syncthreads();
    if (tid < 50) {
        const float y1 = tanh_fast(part[0][tid]);
        const float y2 = tanh_fast(part[1][tid] + part[2][tid]);
        const float y3 = tanh_fast(part[3][tid] + part[4][tid] + part[5][tid]);
        r[tid] = (y1 + y2 + y3) * (1.f / 3.f);
    }
    __syncthreads();

    // Stage 5: gate input projections. g=0..5 = {fi,ff,fg,bi,bf,bg}.
    // Fwd gates land at step s, bwd gates at step 63-s. 25 independent
    // float2 loads per thread (full unroll).
    if (tid < 300) {
        const int g = tid / 50, o = tid - g * 50;
        const float* Wg = (g == 0) ? fiw : (g == 1) ? ffw : (g == 2) ? fgw
                        : (g == 3) ? biw : (g == 4) ? bfw : bgw;
        const float* Bg = (g == 0) ? fib : (g == 1) ? ffb : (g == 2) ? fgb
                        : (g == 3) ? bib : (g == 4) ? bfb : bgb;
        const int sp = (g < 3) ? s : (63 - s);
        const float2* wrow = (const float2*)(Wg + o * 100);   // W[o, 0:50]
        float acc = Bg[o];
#pragma unroll
        for (int j2 = 0; j2 < 25; ++j2) {
            const float2 wv = wrow[j2];
            acc = fmaf(wv.x, r[2 * j2], fmaf(wv.y, r[2 * j2 + 1], acc));
        }
        preW[g * 3200 + sp * 50 + o] = acc;
    }
}

// ---------------- Kernel 2: serial bidirectional scan + output --------------
// 1 block, 128 threads = 2 fully independent waves (wave = direction).
// Lane o holds ALL 3 gates' recurrent weights as 75 packed fp16 half2 ->
// no spill, no barrier, no LDS in the 64-step loop. fp32 accumulation.
// FROZEN since r6: at the serial issue floor (~400 cyc/step).
__global__ __launch_bounds__(128, 1) void scan_kernel(
    const float* __restrict__ preW,      // [6][64][50]
    const float* __restrict__ fiw, const float* __restrict__ ffw,
    const float* __restrict__ fgw, const float* __restrict__ biw,
    const float* __restrict__ bfw, const float* __restrict__ bgw,
    const float* __restrict__ out_w, const float* __restrict__ out_b,
    float* __restrict__ outp)
{
    __shared__ float pre[6][64][50];     // 76.8 KB staged pre-activations
    __shared__ float mh[2][52];          // mean h per direction
    __shared__ float lg[5];              // logits

    const int tid = threadIdx.x;
    const int d = tid >> 6, lane = tid & 63;
    const int oc = (lane < 50) ? lane : 0;     // shadow lanes mirror lane 0

    // Stage preW -> LDS, coalesced float2: 9600 pairs / 128 threads = 75 each.
    {
        const float2* src = (const float2*)preW;
        float2* dst = (float2*)&pre[0][0][0];
#pragma unroll
        for (int k = 0; k < 75; ++k) dst[tid + 128 * k] = src[tid + 128 * k];
    }

    // Recurrent weights W[oc, 50+j] for the 3 gates -> fp16 half2 x 25 each.
    const float* Wi = d ? biw : fiw;
    const float* Wf = d ? bfw : ffw;
    const float* Wg = d ? bgw : fgw;
    __half2 hwi[25], hwf[25], hwg[25];
    {
        const float2* ri = (const float2*)(Wi + oc * 100 + 50);
        const float2* rf = (const float2*)(Wf + oc * 100 + 50);
        const float2* rg = (const float2*)(Wg + oc * 100 + 50);
#pragma unroll
        for (int k = 0; k < 25; ++k) {
            float2 a = ri[k], b = rf[k], c = rg[k];
            hwi[k] = __floats2half2_rn(a.x, a.y);
            hwf[k] = __floats2half2_rn(b.x, b.y);
            hwg[k] = __floats2half2_rn(c.x, c.y);
        }
    }
    __syncthreads();    // pre[] staged; waves are independent from here on

    const int g0 = d * 3;
    float h = 0.f, hsum = 0.f;
    float nai = pre[g0 + 0][0][oc];
    float naf = pre[g0 + 1][0][oc];
    float nag = pre[g0 + 2][0][oc];
#pragma unroll 1
    for (int s2 = 0; s2 < 64; ++s2) {
        float ai = nai, af = naf, ag = nag;
        if (s2 < 63) {                          // ds_read, hidden by matvec
            nai = pre[g0 + 0][s2 + 1][oc];
            naf = pre[g0 + 1][s2 + 1][oc];
            nag = pre[g0 + 2][s2 + 1][oc];
        }
        // 3 independent chains x 2 fma per k; h broadcast via readlane SGPR.
#pragma unroll
        for (int k = 0; k < 25; ++k) {
            const float h0 = rl(h, 2 * k);
            const float h1 = rl(h, 2 * k + 1);
            ai = fmaf(__low2float(hwi[k]), h0, fmaf(__high2float(hwi[k]), h1, ai));
            af = fmaf(__low2float(hwf[k]), h0, fmaf(__high2float(hwf[k]), h1, af));
            ag = fmaf(__low2float(hwg[k]), h0, fmaf(__high2float(hwg[k]), h1, ag));
        }
        h = tanh_fast(fmaf(sigm(ai), tanh_fast(ag), sigm(af) * h));
        hsum += h;
    }
    if (lane < 50) mh[d][lane] = hsum * (1.f / 64.f);
    __syncthreads();

    // Output layer: 5 logits in parallel, then softmax on thread 0.
    if (tid < 5) {
        const float2* wrow = (const float2*)(out_w + tid * 100);
        float acc = out_b[tid];
#pragma unroll
        for (int j2 = 0; j2 < 25; ++j2) {
            float2 wv2 = wrow[j2];
            acc = fmaf(wv2.x, mh[0][2 * j2], fmaf(wv2.y, mh[0][2 * j2 + 1], acc));
        }
#pragma unroll
        for (int j2 = 0; j2 < 25; ++j2) {
            float2 wv2 = wrow[25 + j2];
            acc = fmaf(wv2.x, mh[1][2 * j2], fmaf(wv2.y, mh[1][2 * j2 + 1], acc));
        }
        lg[tid] = acc;
    }
    __syncthreads();
    if (tid == 0) {
        float mx = lg[0];
#pragma unroll
        for (int k = 1; k < 5; ++k) mx = fmaxf(mx, lg[k]);
        float e[5], se = 0.f;
#pragma unroll
        for (int k = 0; k < 5; ++k) { e[k] = __expf(lg[k] - mx); se += e[k]; }
        const float inv = 1.f / se;
#pragma unroll
        for (int k = 0; k < 5; ++k) outp[k] = e[k] * inv;
    }
}

extern "C" void kernel_launch(void* const* d_in, const int* in_sizes, int n_in,
                              void* d_out, int out_size, void* d_ws, size_t ws_size,
                              hipStream_t stream)
{
    (void)in_sizes; (void)n_in; (void)out_size; (void)ws_size;
    const int*   doc  = (const int*)  d_in[0];
    const float* emb  = (const float*)d_in[1];
    const float* wl_w = (const float*)d_in[2];
    const float* wl_b = (const float*)d_in[3];
    const float* c1w  = (const float*)d_in[4];
    const float* c1b  = (const float*)d_in[5];
    const float* c2w  = (const float*)d_in[6];
    const float* c2b  = (const float*)d_in[7];
    const float* c3w  = (const float*)d_in[8];
    const float* c3b  = (const float*)d_in[9];
    const float* fiw  = (const float*)d_in[10];
    const float* fib  = (const float*)d_in[11];
    const float* ffw  = (const float*)d_in[12];
    const float* ffb  = (const float*)d_in[13];
    const float* fgw  = (const float*)d_in[14];
    const float* fgb  = (const float*)d_in[15];
    const float* biw  = (const float*)d_in[16];
    const float* bib  = (const float*)d_in[17];
    const float* bfw  = (const float*)d_in[18];
    const float* bfb  = (const float*)d_in[19];
    const float* bgw  = (const float*)d_in[20];
    const float* bgb  = (const float*)d_in[21];
    const float* ow   = (const float*)d_in[22];
    const float* ob   = (const float*)d_in[23];

    float* preW = (float*)d_ws;          // 6*64*50 floats

    rep_kernel<<<64, 512, 0, stream>>>(doc, emb, wl_w, wl_b,
                                       c1w, c1b, c2w, c2b, c3w, c3b,
                                       fiw, fib, ffw, ffb, fgw, fgb,
                                       biw, bib, bfw, bfb, bgw, bgb, preW);
    scan_kernel<<<1, 128, 0, stream>>>(preW, fiw, ffw, fgw, biw, bfw, bgw,
                                       ow, ob, (float*)d_out);
}

// Round 9
// 237.932 us; speedup vs baseline: 1.5390x; 1.0257x over previous
//
#include <hip/hip_runtime.h>
#include <hip/hip_fp16.h>

// GRNN fused implementation. VOCAB=100000, D=300, H=50, S=64, W=32, OUT=5.
// All fp32 in/out (established rounds 0-3).
//
// Round-9 = round-8 with the compile fix: __builtin_amdgcn_cvt_pkrtz returns
// __fp16-vector, which clang won't implicitly convert to a _Float16-vector;
// bit_cast the packed result directly to unsigned (it is only consumed via
// readlane + bit_cast anyway).
//
// Scan inner loop: v_dot2_f32_f16 (__builtin_amdgcn_fdot2). Weights already
// fp16 (r6, absmax 0.0); h packed once per step into half2 pairs via
// __shfl_xor + v_cvt_pkrtz, so the hot loop is 25 readlane + 75 dot2
// (~115 inst/step) instead of 50 readlane + 150 fma (~220 inst/step).
// rep_kernel frozen from r7.
//
// Algebra: conv branches only need window-means over w of p = x@wl^T + b;
// all 6 windows derive from colsum(x) minus edge rows x0,x1,x30,x31 -> 5
// matvecs (50x300) per sentence instead of a 32x50x300 matmul. h_b reversal
// before the mean is a no-op (mean over steps), so the bwd scan consumes rep
// reversed via projection indexing in rep_kernel stage 5.

typedef _Float16 half2v __attribute__((ext_vector_type(2)));

__device__ __forceinline__ float rl(float v, int j) {
    return __uint_as_float((unsigned)__builtin_amdgcn_readlane(__float_as_uint(v), j));
}
__device__ __forceinline__ unsigned rlu(unsigned v, int j) {
    return (unsigned)__builtin_amdgcn_readlane(v, j);
}
__device__ __forceinline__ float sigm(float x) { return 1.f / (1.f + __expf(-x)); }
__device__ __forceinline__ float tanh_fast(float x) {
    return 1.f - 2.f / (__expf(2.f * x) + 1.f);   // exact at +-inf, ~1e-7 abs err
}

// ---------------- Kernel 1: rep + gate input-projections --------------------
// One block per sentence s, 512 threads (8 waves). FROZEN from r7.
__global__ __launch_bounds__(512, 1) void rep_kernel(
    const int* __restrict__ doc, const float* __restrict__ emb,
    const float* __restrict__ wl_w, const float* __restrict__ wl_b,
    const float* __restrict__ c1w, const float* __restrict__ c1b,
    const float* __restrict__ c2w, const float* __restrict__ c2b,
    const float* __restrict__ c3w, const float* __restrict__ c3b,
    const float* __restrict__ fiw, const float* __restrict__ fib,
    const float* __restrict__ ffw, const float* __restrict__ ffb,
    const float* __restrict__ fgw, const float* __restrict__ fgb,
    const float* __restrict__ biw, const float* __restrict__ bib,
    const float* __restrict__ bfw, const float* __restrict__ bfb,
    const float* __restrict__ bgw, const float* __restrict__ bgb,
    float* __restrict__ preW)            // [6][64][50]
{
    __shared__ float wlw[15000];    // 60 KB: wl_w staged row-major [50][300]
    __shared__ float xL[32][300];   // 38.4 KB: gathered embedding rows
    __shared__ float sv[5][300];    // [colsum, x0, x1, x30, x31]
    __shared__ float Ph[2][5][52];  // stage-2 half-dots
    __shared__ float m[6][52];      // the 6 window means (p-space)
    __shared__ float part[6][52];   // stage-4 partial dots
    __shared__ float r[52];         // rep[s]
    __shared__ int docs[32];

    const int s = blockIdx.x, tid = threadIdx.x;
    if (tid < 32) docs[tid] = doc[s * 32 + tid];
    __syncthreads();

    // Stage 1: stage wl_w -> LDS (3750 float4) and gather 32 emb rows
    // (2400 float4), all loads independent and coalesced.
    {
        const float4* wsrc = (const float4*)wl_w;
        float4* wdst = (float4*)wlw;
#pragma unroll
        for (int k = 0; k < 8; ++k) {           // 8*512 >= 3750
            const int idx = tid + 512 * k;
            if (idx < 3750) wdst[idx] = wsrc[idx];
        }
        const float4* ef4 = (const float4*)emb; // emb row = 75 float4 (16B-aligned)
        float4* xf4 = (float4*)&xL[0][0];
#pragma unroll
        for (int k = 0; k < 5; ++k) {           // 5*512 >= 2400
            const int idx = tid + 512 * k;
            if (idx < 2400) {
                const int rr = idx / 75, c = idx - rr * 75;
                xf4[idx] = ef4[docs[rr] * 75 + c];
            }
        }
    }
    __syncthreads();

    // Stage 1b: column sums + edge rows.
    if (tid < 300) {
        float a = 0.f;
#pragma unroll
        for (int w = 0; w < 32; ++w) a += xL[w][tid];
        sv[0][tid] = a;
        sv[1][tid] = xL[0][tid];
        sv[2][tid] = xL[1][tid];
        sv[3][tid] = xL[30][tid];
        sv[4][tid] = xL[31][tid];
    }
    __syncthreads();

    // Stage 2: 500 half-dot tasks: Ph[hf][v][i] = wlw[i, hf*150:+150].sv[v,..]
    if (tid < 500) {
        const int i = tid / 10, rem = tid - i * 10, v = rem >> 1, hf = rem & 1;
        const float2* w2 = (const float2*)(wlw + i * 300 + hf * 150);
        const float2* x2 = (const float2*)(sv[v] + hf * 150);
        float a0 = 0.f, a1 = 0.f;
#pragma unroll
        for (int k = 0; k < 75; ++k) {
            const float2 w = w2[k], x = x2[k];
            a0 = fmaf(w.x, x.x, a0);
            a1 = fmaf(w.y, x.y, a1);
        }
        Ph[hf][v][i] = a0 + a1;
    }
    __syncthreads();

    // Stage 3: the 6 window means. mean = Qwin/len + wl_b.
    if (tid < 50) {
        const int i = tid;
        const float b   = wl_b[i];
        const float QA  = Ph[0][0][i] + Ph[1][0][i];
        const float Q0  = Ph[0][1][i] + Ph[1][1][i];
        const float Q1  = Ph[0][2][i] + Ph[1][2][i];
        const float Q30 = Ph[0][3][i] + Ph[1][3][i];
        const float Q31 = Ph[0][4][i] + Ph[1][4][i];
        m[0][i] = QA * (1.f / 32.f) + b;
        m[1][i] = (QA - Q31) * (1.f / 31.f) + b;
        m[2][i] = (QA - Q0)  * (1.f / 31.f) + b;
        m[3][i] = (QA - Q30 - Q31) * (1.f / 30.f) + b;
        m[4][i] = (QA - Q0  - Q31) * (1.f / 30.f) + b;
        m[5][i] = (QA - Q0  - Q1 ) * (1.f / 30.f) + b;
    }
    __syncthreads();

    // Stage 4: 6 parallel partial dots, full unroll, 2 accumulator chains.
    if (tid < 300) {
        const int q = tid / 50, o = tid - q * 50;
        const float* base = (q == 0) ? c1w : (q < 3) ? c2w : c3w;
        const int str = (q == 0) ? 1 : (q < 3) ? 2 : 3;
        const int off = (q == 0) ? 0 : (q < 3) ? (q - 1) : (q - 3);
        float a0 = (q == 0) ? c1b[o] : (q == 1) ? c2b[o] : (q == 3) ? c3b[o] : 0.f;
        float a1 = 0.f;
        const float* mp = m[q];
#pragma unroll
        for (int i = 0; i < 50; i += 2) {
            a0 = fmaf(base[(o * 50 + i)     * str + off], mp[i],     a0);
            a1 = fmaf(base[(o * 50 + i + 1) * str + off], mp[i + 1], a1);
        }
        part[q][o] = a0 + a1;
    }
    __syncthreads();
    if (tid < 50) {
        const float y1 = tanh_fast(part[0][tid]);
        const float y2 = tanh_fast(part[1][tid] + part[2][tid]);
        const float y3 = tanh_fast(part[3][tid] + part[4][tid] + part[5][tid]);
        r[tid] = (y1 + y2 + y3) * (1.f / 3.f);
    }
    __syncthreads();

    // Stage 5: gate input projections. g=0..5 = {fi,ff,fg,bi,bf,bg}.
    if (tid < 300) {
        const int g = tid / 50, o = tid - g * 50;
        const float* Wg = (g == 0) ? fiw : (g == 1) ? ffw : (g == 2) ? fgw
                        : (g == 3) ? biw : (g == 4) ? bfw : bgw;
        const float* Bg = (g == 0) ? fib : (g == 1) ? ffb : (g == 2) ? fgb
                        : (g == 3) ? bib : (g == 4) ? bfb : bgb;
        const int sp = (g < 3) ? s : (63 - s);
        const float2* wrow = (const float2*)(Wg + o * 100);   // W[o, 0:50]
        float acc = Bg[o];
#pragma unroll
        for (int j2 = 0; j2 < 25; ++j2) {
            const float2 wv = wrow[j2];
            acc = fmaf(wv.x, r[2 * j2], fmaf(wv.y, r[2 * j2 + 1], acc));
        }
        preW[g * 3200 + sp * 50 + o] = acc;
    }
}

// ---------------- Kernel 2: serial bidirectional scan + output --------------
// 1 block, 128 threads = 2 independent waves (wave = direction). Lane o holds
// all 150 recurrent weights as fp16 pairs; hot loop = 25 readlane + 75
// v_dot2_f32_f16 per step (h packed into half2 pairs via shfl_xor+pkrtz).
__global__ __launch_bounds__(128, 1) void scan_kernel(
    const float* __restrict__ preW,      // [6][64][50]
    const float* __restrict__ fiw, const float* __restrict__ ffw,
    const float* __restrict__ fgw, const float* __restrict__ biw,
    const float* __restrict__ bfw, const float* __restrict__ bgw,
    const float* __restrict__ out_w, const float* __restrict__ out_b,
    float* __restrict__ outp)
{
    __shared__ float pre[6][64][50];     // 76.8 KB staged pre-activations
    __shared__ float mh[2][52];          // mean h per direction
    __shared__ float lg[5];              // logits

    const int tid = threadIdx.x;
    const int d = tid >> 6, lane = tid & 63;
    const int oc = (lane < 50) ? lane : 0;     // shadow lanes mirror lane 0

    // Stage preW -> LDS, coalesced float2: 9600 pairs / 128 threads = 75 each.
    {
        const float2* src = (const float2*)preW;
        float2* dst = (float2*)&pre[0][0][0];
#pragma unroll
        for (int k = 0; k < 75; ++k) dst[tid + 128 * k] = src[tid + 128 * k];
    }

    // Recurrent weights W[oc, 50+j] for the 3 gates -> fp16 pairs x 25 each.
    const float* Wi = d ? biw : fiw;
    const float* Wf = d ? bfw : ffw;
    const float* Wg = d ? bgw : fgw;
    half2v hwi[25], hwf[25], hwg[25];
    {
        const float2* ri = (const float2*)(Wi + oc * 100 + 50);
        const float2* rf = (const float2*)(Wf + oc * 100 + 50);
        const float2* rg = (const float2*)(Wg + oc * 100 + 50);
#pragma unroll
        for (int k = 0; k < 25; ++k) {
            float2 a = ri[k], b = rf[k], c = rg[k];
            hwi[k].x = (_Float16)a.x; hwi[k].y = (_Float16)a.y;  // rn converts
            hwf[k].x = (_Float16)b.x; hwf[k].y = (_Float16)b.y;
            hwg[k].x = (_Float16)c.x; hwg[k].y = (_Float16)c.y;
        }
    }
    __syncthreads();    // pre[] staged; waves are independent from here on

    const int g0 = d * 3;
    float h = 0.f, hsum = 0.f;
    float nai = pre[g0 + 0][0][oc];
    float naf = pre[g0 + 1][0][oc];
    float nag = pre[g0 + 2][0][oc];
#pragma unroll 1
    for (int s2 = 0; s2 < 64; ++s2) {
        // Pack (h_lane, h_lane^1) into a half2 once; even lanes hold the
        // in-order pair (h_2k, h_2k+1) -> 25 readlanes feed all 3 gates.
        const float hx = __shfl_xor(h, 1, 64);
        const unsigned hpu =
            __builtin_bit_cast(unsigned, __builtin_amdgcn_cvt_pkrtz(h, hx));

        float ai0 = nai, af0 = naf, ag0 = nag;
        float ai1 = 0.f, af1 = 0.f, ag1 = 0.f;
        if (s2 < 63) {                          // ds_read, hidden by matvec
            nai = pre[g0 + 0][s2 + 1][oc];
            naf = pre[g0 + 1][s2 + 1][oc];
            nag = pre[g0 + 2][s2 + 1][oc];
        }
#if __has_builtin(__builtin_amdgcn_fdot2)
#pragma unroll
        for (int k = 0; k < 24; k += 2) {
            const half2v p0 = __builtin_bit_cast(half2v, rlu(hpu, 2 * k));
            const half2v p1 = __builtin_bit_cast(half2v, rlu(hpu, 2 * k + 2));
            ai0 = __builtin_amdgcn_fdot2(hwi[k],     p0, ai0, false);
            af0 = __builtin_amdgcn_fdot2(hwf[k],     p0, af0, false);
            ag0 = __builtin_amdgcn_fdot2(hwg[k],     p0, ag0, false);
            ai1 = __builtin_amdgcn_fdot2(hwi[k + 1], p1, ai1, false);
            af1 = __builtin_amdgcn_fdot2(hwf[k + 1], p1, af1, false);
            ag1 = __builtin_amdgcn_fdot2(hwg[k + 1], p1, ag1, false);
        }
        {
            const half2v p = __builtin_bit_cast(half2v, rlu(hpu, 48));
            ai0 = __builtin_amdgcn_fdot2(hwi[24], p, ai0, false);
            af0 = __builtin_amdgcn_fdot2(hwf[24], p, af0, false);
            ag0 = __builtin_amdgcn_fdot2(hwg[24], p, ag0, false);
        }
#else
#pragma unroll
        for (int k = 0; k < 25; ++k) {
            const float h0 = rl(h, 2 * k);
            const float h1 = rl(h, 2 * k + 1);
            ai0 = fmaf((float)hwi[k].x, h0, fmaf((float)hwi[k].y, h1, ai0));
            af0 = fmaf((float)hwf[k].x, h0, fmaf((float)hwf[k].y, h1, af0));
            ag0 = fmaf((float)hwg[k].x, h0, fmaf((float)hwg[k].y, h1, ag0));
        }
#endif
        const float ai = ai0 + ai1, af = af0 + af1, ag = ag0 + ag1;
        h = tanh_fast(fmaf(sigm(ai), tanh_fast(ag), sigm(af) * h));
        hsum += h;
    }
    if (lane < 50) mh[d][lane] = hsum * (1.f / 64.f);
    __syncthreads();

    // Output layer: 5 logits in parallel, then softmax on thread 0.
    if (tid < 5) {
        const float2* wrow = (const float2*)(out_w + tid * 100);
        float acc = out_b[tid];
#pragma unroll
        for (int j2 = 0; j2 < 25; ++j2) {
            float2 wv2 = wrow[j2];
            acc = fmaf(wv2.x, mh[0][2 * j2], fmaf(wv2.y, mh[0][2 * j2 + 1], acc));
        }
#pragma unroll
        for (int j2 = 0; j2 < 25; ++j2) {
            float2 wv2 = wrow[25 + j2];
            acc = fmaf(wv2.x, mh[1][2 * j2], fmaf(wv2.y, mh[1][2 * j2 + 1], acc));
        }
        lg[tid] = acc;
    }
    __syncthreads();
    if (tid == 0) {
        float mx = lg[0];
#pragma unroll
        for (int k = 1; k < 5; ++k) mx = fmaxf(mx, lg[k]);
        float e[5], se = 0.f;
#pragma unroll
        for (int k = 0; k < 5; ++k) { e[k] = __expf(lg[k] - mx); se += e[k]; }
        const float inv = 1.f / se;
#pragma unroll
        for (int k = 0; k < 5; ++k) outp[k] = e[k] * inv;
    }
}

extern "C" void kernel_launch(void* const* d_in, const int* in_sizes, int n_in,
                              void* d_out, int out_size, void* d_ws, size_t ws_size,
                              hipStream_t stream)
{
    (void)in_sizes; (void)n_in; (void)out_size; (void)ws_size;
    const int*   doc  = (const int*)  d_in[0];
    const float* emb  = (const float*)d_in[1];
    const float* wl_w = (const float*)d_in[2];
    const float* wl_b = (const float*)d_in[3];
    const float* c1w  = (const float*)d_in[4];
    const float* c1b  = (const float*)d_in[5];
    const float* c2w  = (const float*)d_in[6];
    const float* c2b  = (const float*)d_in[7];
    const float* c3w  = (const float*)d_in[8];
    const float* c3b  = (const float*)d_in[9];
    const float* fiw  = (const float*)d_in[10];
    const float* fib  = (const float*)d_in[11];
    const float* ffw  = (const float*)d_in[12];
    const float* ffb  = (const float*)d_in[13];
    const float* fgw  = (const float*)d_in[14];
    const float* fgb  = (const float*)d_in[15];
    const float* biw  = (const float*)d_in[16];
    const float* bib  = (const float*)d_in[17];
    const float* bfw  = (const float*)d_in[18];
    const float* bfb  = (const float*)d_in[19];
    const float* bgw  = (const float*)d_in[20];
    const float* bgb  = (const float*)d_in[21];
    const float* ow   = (const float*)d_in[22];
    const float* ob   = (const float*)d_in[23];

    float* preW = (float*)d_ws;          // 6*64*50 floats

    rep_kernel<<<64, 512, 0, stream>>>(doc, emb, wl_w, wl_b,
                                       c1w, c1b, c2w, c2b, c3w, c3b,
                                       fiw, fib, ffw, ffb, fgw, fgb,
                                       biw, bib, bfw, bfb, bgw, bgb, preW);
    scan_kernel<<<1, 128, 0, stream>>>(preW, fiw, ffw, fgw, biw, bfw, bgw,
                                       ow, ob, (float*)d_out);
}